// Round 4
// baseline (2744.954 us; speedup 1.0000x reference)
//
#include <hip/hip_runtime.h>

typedef __bf16 bf16x8 __attribute__((ext_vector_type(8)));
typedef float  f32x4  __attribute__((ext_vector_type(4)));
typedef unsigned long long u64;

#define AGENT __HIP_MEMORY_SCOPE_AGENT
#define MFMA  __builtin_amdgcn_mfma_f32_16x16x32_bf16

__device__ __forceinline__ float fast_tanh(float x) {
    float e = __expf(2.0f * x);
    return 1.0f - 2.0f * __builtin_amdgcn_rcpf(e + 1.0f);
}

// Raw barrier: drain ONLY LDS ops; global loads/stores stay in flight.
__device__ __forceinline__ void lds_barrier() {
    asm volatile("s_waitcnt lgkmcnt(0)" ::: "memory");
    __builtin_amdgcn_s_barrier();
}

// ---------------------------------------------------------------------------
// Kernel 1: xproj = x @ Wih^T + bih -> fp32 into d_out's states region.
// ---------------------------------------------------------------------------
__global__ __launch_bounds__(256) void xproj_gemm_kernel(
    const float* __restrict__ x, const float* __restrict__ Wih,
    const float* __restrict__ bih, float* __restrict__ out)
{
    __shared__ __bf16 Ash[64][72];
    __shared__ __bf16 Bsh[64][72];

    const int tid  = threadIdx.x;
    const int wave = tid >> 6, lane = tid & 63;
    const int col  = lane & 15, kq = lane >> 4;
    const int bt0  = blockIdx.x * 64;
    const int h0   = blockIdx.y * 64;

    f32x4 acc[4];
#pragma unroll
    for (int nt = 0; nt < 4; ++nt) acc[nt] = (f32x4){0.f, 0.f, 0.f, 0.f};

    const int r  = tid >> 2;
    const int cb = (tid & 3) * 16;

    for (int k0 = 0; k0 < 512; k0 += 64) {
        const float* ax = x   + (size_t)(bt0 + r) * 512 + k0 + cb;
        const float* bx = Wih + (size_t)(h0  + r) * 512 + k0 + cb;
#pragma unroll
        for (int j = 0; j < 4; ++j) {
            const float4 av = ((const float4*)ax)[j];
            const float4 bv = ((const float4*)bx)[j];
            const int c = cb + 4 * j;
            Ash[r][c+0]=(__bf16)av.x; Ash[r][c+1]=(__bf16)av.y;
            Ash[r][c+2]=(__bf16)av.z; Ash[r][c+3]=(__bf16)av.w;
            Bsh[r][c+0]=(__bf16)bv.x; Bsh[r][c+1]=(__bf16)bv.y;
            Bsh[r][c+2]=(__bf16)bv.z; Bsh[r][c+3]=(__bf16)bv.w;
        }
        __syncthreads();
#pragma unroll
        for (int kt = 0; kt < 2; ++kt) {
            bf16x8 a = *(const bf16x8*)&Ash[wave * 16 + col][kt * 32 + kq * 8];
#pragma unroll
            for (int nt = 0; nt < 4; ++nt) {
                bf16x8 bb = *(const bf16x8*)&Bsh[nt * 16 + col][kt * 32 + kq * 8];
                acc[nt] = MFMA(a, bb, acc[nt], 0, 0, 0);
            }
        }
        __syncthreads();
    }
#pragma unroll
    for (int nt = 0; nt < 4; ++nt) {
        const float bv = bih[h0 + nt * 16 + col];
#pragma unroll
        for (int reg = 0; reg < 4; ++reg) {
            const int m = bt0 + wave * 16 + kq * 4 + reg;
            out[(size_t)m * 512 + h0 + nt * 16 + col] = acc[nt][reg] + bv;
        }
    }
}

// ---------------------------------------------------------------------------
// Kernel 2: recurrence. 64 blocks = 16 batch-pairs x 4 weight-stationary
// slices. Each block runs TWO independent batches (same slice -> shared wf
// registers) as alternating segments; poll loads for batch s are
// prefetch-issued during batch s^1's segment so the agent-scope mailbox
// round-trip (HBM-level, rounds 2-3 proved it can't be cached) overlaps the
// other batch's compute instead of stalling the step.
// ---------------------------------------------------------------------------
__global__ __launch_bounds__(256) void lagrange_rnn_kernel(
    const float* __restrict__ Whh, const float* __restrict__ bhh,
    const float* __restrict__ kern, float* __restrict__ out,
    u64* __restrict__ mbox)
{
    const int id   = blockIdx.x;                 // 0..63
    const int p    = id & 3;                     // slice member 0..3
    const int q    = id >> 2;                    // batch pair 0..15
    const int b0   = q * 2, b1 = q * 2 + 1;
    const int tid  = threadIdx.x;
    const int wave = tid >> 6, lane = tid & 63;
    const int col  = lane & 15, kq = lane >> 4;

    __shared__ float  hist[2][4][512];    // per-batch circular h history, fp32
    __shared__ __bf16 hread[2][2][512];   // per-batch parity-dbuf MFMA A operand
    __shared__ float  xpb[2][2][128];     // per-batch parity-dbuf xp (wave0-fed)

    for (int i = tid; i < 4096; i += 256) ((float*)hist)[i] = 0.f;
    for (int i = tid; i < 2048; i += 256) ((__bf16*)hread)[i] = (__bf16)0.f;

    // --- weight fragments, K-reordered: wf[j] <-> global K-tile (4p+j)&15
    const int hA = p * 128 + wave * 32 + col;
    const int hB = hA + 16;
    bf16x8 wf0[16], wf1[16];
#pragma unroll
    for (int j = 0; j < 16; ++j) {
        const int ktg = ((j + 4 * p) & 15) * 32 + kq * 8;
        const float* s0 = Whh + (size_t)hA * 512 + ktg;
        const float* s1 = Whh + (size_t)hB * 512 + ktg;
        const float4 a0 = *(const float4*)s0, a1 = *(const float4*)(s0 + 4);
        const float4 c0 = *(const float4*)s1, c1 = *(const float4*)(s1 + 4);
        bf16x8 w;
        w[0]=(__bf16)a0.x; w[1]=(__bf16)a0.y; w[2]=(__bf16)a0.z; w[3]=(__bf16)a0.w;
        w[4]=(__bf16)a1.x; w[5]=(__bf16)a1.y; w[6]=(__bf16)a1.z; w[7]=(__bf16)a1.w;
        wf0[j] = w;
        w[0]=(__bf16)c0.x; w[1]=(__bf16)c0.y; w[2]=(__bf16)c0.z; w[3]=(__bf16)c0.w;
        w[4]=(__bf16)c1.x; w[5]=(__bf16)c1.y; w[6]=(__bf16)c1.z; w[7]=(__bf16)c1.w;
        wf1[j] = w;
    }
    const float k0 = kern[0], k1 = kern[1], k2 = kern[2], k3 = kern[3];
    const float bA = bhh[hA], bB = bhh[hB];
    float* st0 = out + (size_t)b0 * 1024 * 512 + hA;
    float* st1 = out + (size_t)b1 * 1024 * 512 + hA;
    const float* xs0 = out + (size_t)b0 * 1024 * 512 + p * 128 + lane * 2;
    const float* xs1 = out + (size_t)b1 * 1024 * 512 + p * 128 + lane * 2;
    const int peer = (p + wave) & 3;              // waves 1..3 poll this peer
    const int j0 = peer * 128 + lane * 2;
    const bool comp = (lane < 16);
    const int abase = p * 128 + kq * 8;           // j-th A addr = (abase+32j)&511
    const int xslot = wave * 32 + col;

    if (wave == 0) {                              // preload xp(0) both batches
        const float2 x0 = *(const float2*)xs0;
        const float2 x1 = *(const float2*)xs1;
        xpb[0][0][lane * 2] = x0.x; xpb[0][0][lane * 2 + 1] = x0.y;
        xpb[1][0][lane * 2] = x1.x; xpb[1][0][lane * 2 + 1] = x1.y;
    }
    __syncthreads();

    u64 pva0 = 0, pva1 = 0;   // prefetched poll regs, batch b0
    u64 pvb0 = 0, pvb1 = 0;   // prefetched poll regs, batch b1

    for (int t = 0; t < 1024; ++t) {
        const int rb = t & 1, wb = rb ^ 1;
        const int rt = t & 3;
        const int rm1 = (t + 3) & 3, rm2 = (t + 2) & 3, rm3 = (t + 1) & 3;
        const unsigned want = (unsigned)t;

        // wave0: issue xp(t+1) prefetch for BOTH batches (drained at deposits)
        float2 nx0 = {0.f, 0.f}, nx1 = {0.f, 0.f};
        if (wave == 0) {
            nx0 = *(const float2*)(xs0 + (size_t)(t + 1) * 512);
            nx1 = *(const float2*)(xs1 + (size_t)(t + 1) * 512);
        }

        // ==================== segment 0 : batch b0, step t ====================
        lds_barrier();                             // barA0
        f32x4 acc0 = (f32x4){0,0,0,0}, acc1 = (f32x4){0,0,0,0};
#pragma unroll
        for (int j = 0; j < 4; ++j) {
            bf16x8 a = *(const bf16x8*)&hread[0][rb][(abase + 32 * j) & 511];
            acc0 = MFMA(a, wf0[j], acc0, 0, 0, 0);
            acc1 = MFMA(a, wf1[j], acc1, 0, 0, 0);
        }
        if (wave != 0 && t) {
            u64 v0 = pva0, v1 = pva1;             // prefetched one segment ago
            if ((unsigned)(v0 >> 32) != want || (unsigned)(v1 >> 32) != want) {
                const u64* mg = mbox + (size_t)(((b0 << 1) | rb) * 4 + peer) * 128 + lane * 2;
                do {
                    v0 = __hip_atomic_load(&mg[0], __ATOMIC_RELAXED, AGENT);
                    v1 = __hip_atomic_load(&mg[1], __ATOMIC_RELAXED, AGENT);
                } while ((unsigned)(v0 >> 32) != want || (unsigned)(v1 >> 32) != want);
            }
            union { unsigned u; float f; } d0, d1;
            d0.u = (unsigned)v0; d1.u = (unsigned)v1;
            const float q0 = k1 * hist[0][rm2][j0]     + k2 * hist[0][rm3][j0]     + k3 * hist[0][rt][j0];
            const float q1 = k1 * hist[0][rm2][j0 + 1] + k2 * hist[0][rm3][j0 + 1] + k3 * hist[0][rt][j0 + 1];
            hread[0][rb][j0]     = (__bf16)(q0 + k0 * d0.f);
            hread[0][rb][j0 + 1] = (__bf16)(q1 + k0 * d1.f);
            hist[0][rm1][j0]     = d0.f;
            hist[0][rm1][j0 + 1] = d1.f;
        }
        lds_barrier();                             // barB0
        // --- prefetch-issue polls for (b1, t): ships aged ~1 segment already
        if (wave != 0 && t) {
            const u64* mg = mbox + (size_t)(((b1 << 1) | rb) * 4 + peer) * 128 + lane * 2;
            pvb0 = __hip_atomic_load(&mg[0], __ATOMIC_RELAXED, AGENT);
            pvb1 = __hip_atomic_load(&mg[1], __ATOMIC_RELAXED, AGENT);
        }
        float xAv = 0.f, xBv = 0.f, ppA = 0.f, ppB = 0.f;
        if (comp) {
            xAv = xpb[0][rb][xslot];
            xBv = xpb[0][rb][xslot + 16];
            ppA = k1 * hist[0][rm1][hA] + k2 * hist[0][rm2][hA] + k3 * hist[0][rm3][hA];
            ppB = k1 * hist[0][rm1][hB] + k2 * hist[0][rm2][hB] + k3 * hist[0][rm3][hB];
        }
        f32x4 c0a = (f32x4){0,0,0,0}, c0b = (f32x4){0,0,0,0}, c0c = (f32x4){0,0,0,0};
        f32x4 c1a = (f32x4){0,0,0,0}, c1b = (f32x4){0,0,0,0}, c1c = (f32x4){0,0,0,0};
#pragma unroll
        for (int j = 4; j < 8; ++j) {
            bf16x8 a = *(const bf16x8*)&hread[0][rb][(abase + 32 * j) & 511];
            c0a = MFMA(a, wf0[j], c0a, 0, 0, 0);
            c1a = MFMA(a, wf1[j], c1a, 0, 0, 0);
        }
#pragma unroll
        for (int j = 8; j < 12; ++j) {
            bf16x8 a = *(const bf16x8*)&hread[0][rb][(abase + 32 * j) & 511];
            c0b = MFMA(a, wf0[j], c0b, 0, 0, 0);
            c1b = MFMA(a, wf1[j], c1b, 0, 0, 0);
        }
#pragma unroll
        for (int j = 12; j < 16; ++j) {
            bf16x8 a = *(const bf16x8*)&hread[0][rb][(abase + 32 * j) & 511];
            c0c = MFMA(a, wf0[j], c0c, 0, 0, 0);
            c1c = MFMA(a, wf1[j], c1c, 0, 0, 0);
        }
        if (comp) {
            const float hAv = fast_tanh(xAv + acc0[0] + c0a[0] + c0b[0] + c0c[0] + bA);
            const float hBv = fast_tanh(xBv + acc1[0] + c1a[0] + c1b[0] + c1c[0] + bB);
            u64* ms = mbox + (size_t)(((b0 << 1) | wb) * 4 + p) * 128;
            const u64 tag = (u64)(unsigned)(t + 1) << 32;
            union { float f; unsigned u; } cA, cB;
            cA.f = hAv; cB.f = hBv;
            __hip_atomic_store(&ms[wave * 32 + col],      tag | cA.u, __ATOMIC_RELAXED, AGENT);
            __hip_atomic_store(&ms[wave * 32 + col + 16], tag | cB.u, __ATOMIC_RELAXED, AGENT);
            st0[(size_t)t * 512]      = hAv;
            st0[(size_t)t * 512 + 16] = hBv;
            hist[0][rt][hA] = hAv;  hread[0][wb][hA] = (__bf16)(ppA + k0 * hAv);
            hist[0][rt][hB] = hBv;  hread[0][wb][hB] = (__bf16)(ppB + k0 * hBv);
        }
        if (wave == 0) {
            xpb[0][wb][lane * 2]     = nx0.x;
            xpb[0][wb][lane * 2 + 1] = nx0.y;
        }

        // ==================== segment 1 : batch b1, step t ====================
        lds_barrier();                             // barA1
        f32x4 e0 = (f32x4){0,0,0,0}, e1 = (f32x4){0,0,0,0};
#pragma unroll
        for (int j = 0; j < 4; ++j) {
            bf16x8 a = *(const bf16x8*)&hread[1][rb][(abase + 32 * j) & 511];
            e0 = MFMA(a, wf0[j], e0, 0, 0, 0);
            e1 = MFMA(a, wf1[j], e1, 0, 0, 0);
        }
        if (wave != 0 && t) {
            u64 v0 = pvb0, v1 = pvb1;             // prefetched mid-segment-0
            if ((unsigned)(v0 >> 32) != want || (unsigned)(v1 >> 32) != want) {
                const u64* mg = mbox + (size_t)(((b1 << 1) | rb) * 4 + peer) * 128 + lane * 2;
                do {
                    v0 = __hip_atomic_load(&mg[0], __ATOMIC_RELAXED, AGENT);
                    v1 = __hip_atomic_load(&mg[1], __ATOMIC_RELAXED, AGENT);
                } while ((unsigned)(v0 >> 32) != want || (unsigned)(v1 >> 32) != want);
            }
            union { unsigned u; float f; } d0, d1;
            d0.u = (unsigned)v0; d1.u = (unsigned)v1;
            const float q0 = k1 * hist[1][rm2][j0]     + k2 * hist[1][rm3][j0]     + k3 * hist[1][rt][j0];
            const float q1 = k1 * hist[1][rm2][j0 + 1] + k2 * hist[1][rm3][j0 + 1] + k3 * hist[1][rt][j0 + 1];
            hread[1][rb][j0]     = (__bf16)(q0 + k0 * d0.f);
            hread[1][rb][j0 + 1] = (__bf16)(q1 + k0 * d1.f);
            hist[1][rm1][j0]     = d0.f;
            hist[1][rm1][j0 + 1] = d1.f;
        }
        lds_barrier();                             // barB1
        // --- prefetch-issue polls for (b0, t+1): ships happened in segment 0
        if (wave != 0) {
            const u64* mg = mbox + (size_t)(((b0 << 1) | wb) * 4 + peer) * 128 + lane * 2;
            pva0 = __hip_atomic_load(&mg[0], __ATOMIC_RELAXED, AGENT);
            pva1 = __hip_atomic_load(&mg[1], __ATOMIC_RELAXED, AGENT);
        }
        float yAv = 0.f, yBv = 0.f, qpA = 0.f, qpB = 0.f;
        if (comp) {
            yAv = xpb[1][rb][xslot];
            yBv = xpb[1][rb][xslot + 16];
            qpA = k1 * hist[1][rm1][hA] + k2 * hist[1][rm2][hA] + k3 * hist[1][rm3][hA];
            qpB = k1 * hist[1][rm1][hB] + k2 * hist[1][rm2][hB] + k3 * hist[1][rm3][hB];
        }
        f32x4 g0a = (f32x4){0,0,0,0}, g0b = (f32x4){0,0,0,0}, g0c = (f32x4){0,0,0,0};
        f32x4 g1a = (f32x4){0,0,0,0}, g1b = (f32x4){0,0,0,0}, g1c = (f32x4){0,0,0,0};
#pragma unroll
        for (int j = 4; j < 8; ++j) {
            bf16x8 a = *(const bf16x8*)&hread[1][rb][(abase + 32 * j) & 511];
            g0a = MFMA(a, wf0[j], g0a, 0, 0, 0);
            g1a = MFMA(a, wf1[j], g1a, 0, 0, 0);
        }
#pragma unroll
        for (int j = 8; j < 12; ++j) {
            bf16x8 a = *(const bf16x8*)&hread[1][rb][(abase + 32 * j) & 511];
            g0b = MFMA(a, wf0[j], g0b, 0, 0, 0);
            g1b = MFMA(a, wf1[j], g1b, 0, 0, 0);
        }
#pragma unroll
        for (int j = 12; j < 16; ++j) {
            bf16x8 a = *(const bf16x8*)&hread[1][rb][(abase + 32 * j) & 511];
            g0c = MFMA(a, wf0[j], g0c, 0, 0, 0);
            g1c = MFMA(a, wf1[j], g1c, 0, 0, 0);
        }
        if (comp) {
            const float hAv = fast_tanh(yAv + e0[0] + g0a[0] + g0b[0] + g0c[0] + bA);
            const float hBv = fast_tanh(yBv + e1[0] + g1a[0] + g1b[0] + g1c[0] + bB);
            u64* ms = mbox + (size_t)(((b1 << 1) | wb) * 4 + p) * 128;
            const u64 tag = (u64)(unsigned)(t + 1) << 32;
            union { float f; unsigned u; } cA, cB;
            cA.f = hAv; cB.f = hBv;
            __hip_atomic_store(&ms[wave * 32 + col],      tag | cA.u, __ATOMIC_RELAXED, AGENT);
            __hip_atomic_store(&ms[wave * 32 + col + 16], tag | cB.u, __ATOMIC_RELAXED, AGENT);
            st1[(size_t)t * 512]      = hAv;
            st1[(size_t)t * 512 + 16] = hBv;
            hist[1][rt][hA] = hAv;  hread[1][wb][hA] = (__bf16)(qpA + k0 * hAv);
            hist[1][rt][hB] = hBv;  hread[1][wb][hB] = (__bf16)(qpB + k0 * hBv);
        }
        if (wave == 0) {
            xpb[1][wb][lane * 2]     = nx1.x;
            xpb[1][wb][lane * 2 + 1] = nx1.y;
        }
    }

    // final state output: each block writes its OWN slice of h(1023) (row 3)
    float* o0 = out + (size_t)32 * 1024 * 512 + (size_t)b0 * 512;
    float* o1 = out + (size_t)32 * 1024 * 512 + (size_t)b1 * 512;
    if (comp) {
        o0[hA] = hist[0][3][hA];
        o0[hB] = hist[0][3][hB];
        o1[hA] = hist[1][3][hA];
        o1[hB] = hist[1][3][hB];
    }
}

// ---------------------------------------------------------------------------
extern "C" void kernel_launch(void* const* d_in, const int* in_sizes, int n_in,
                              void* d_out, int out_size, void* d_ws, size_t ws_size,
                              hipStream_t stream) {
    const float* x    = (const float*)d_in[0];   // [32,1024,512]
    const float* Wih  = (const float*)d_in[1];   // [512,512]
    const float* Whh  = (const float*)d_in[2];   // [512,512]
    const float* bih  = (const float*)d_in[3];   // [512]
    const float* bhh  = (const float*)d_in[4];   // [512]
    const float* kern = (const float*)d_in[5];   // [4]
    float* out = (float*)d_out;

    // mailbox: 32 batches x 2 parity x 4 slices x 128 tagged u64 = 256 KB.
    // No init needed: exact tag match; workspace poison can't match a tag.
    u64* mbox = (u64*)d_ws;

    dim3 g1(512, 8, 1);
    xproj_gemm_kernel<<<g1, 256, 0, stream>>>(x, Wih, bih, out);
    lagrange_rnn_kernel<<<64, 256, 0, stream>>>(Whh, bhh, kern, out, mbox);
}

// Round 6
// 2661.052 us; speedup vs baseline: 1.0315x; 1.0315x over previous
//
#include <hip/hip_runtime.h>

typedef __bf16 bf16x8 __attribute__((ext_vector_type(8)));
typedef float  f32x4  __attribute__((ext_vector_type(4)));
typedef unsigned long long u64;

#define AGENT __HIP_MEMORY_SCOPE_AGENT
#define MFMA  __builtin_amdgcn_mfma_f32_16x16x32_bf16

__device__ __forceinline__ float fast_tanh(float x) {
    float e = __expf(2.0f * x);
    return 1.0f - 2.0f * __builtin_amdgcn_rcpf(e + 1.0f);
}

// Raw barrier: drain ONLY LDS ops; global loads/stores stay in flight.
__device__ __forceinline__ void lds_barrier() {
    asm volatile("s_waitcnt lgkmcnt(0)" ::: "memory");
    __builtin_amdgcn_s_barrier();
}

// ---------------------------------------------------------------------------
// Kernel 1: xproj = x @ Wih^T + (bih + bhh) -> fp32 into d_out states region.
// bhh folded here so the RNN tanh input is xp + h_read@Whh^T directly.
// ---------------------------------------------------------------------------
__global__ __launch_bounds__(256) void xproj_gemm_kernel(
    const float* __restrict__ x, const float* __restrict__ Wih,
    const float* __restrict__ bih, const float* __restrict__ bhh,
    float* __restrict__ out)
{
    __shared__ __bf16 Ash[64][72];
    __shared__ __bf16 Bsh[64][72];

    const int tid  = threadIdx.x;
    const int wave = tid >> 6, lane = tid & 63;
    const int col  = lane & 15, kq = lane >> 4;
    const int bt0  = blockIdx.x * 64;
    const int h0   = blockIdx.y * 64;

    f32x4 acc[4];
#pragma unroll
    for (int nt = 0; nt < 4; ++nt) acc[nt] = (f32x4){0.f, 0.f, 0.f, 0.f};

    const int r  = tid >> 2;
    const int cb = (tid & 3) * 16;

    for (int k0 = 0; k0 < 512; k0 += 64) {
        const float* ax = x   + (size_t)(bt0 + r) * 512 + k0 + cb;
        const float* bx = Wih + (size_t)(h0  + r) * 512 + k0 + cb;
#pragma unroll
        for (int j = 0; j < 4; ++j) {
            const float4 av = ((const float4*)ax)[j];
            const float4 bv = ((const float4*)bx)[j];
            const int c = cb + 4 * j;
            Ash[r][c+0]=(__bf16)av.x; Ash[r][c+1]=(__bf16)av.y;
            Ash[r][c+2]=(__bf16)av.z; Ash[r][c+3]=(__bf16)av.w;
            Bsh[r][c+0]=(__bf16)bv.x; Bsh[r][c+1]=(__bf16)bv.y;
            Bsh[r][c+2]=(__bf16)bv.z; Bsh[r][c+3]=(__bf16)bv.w;
        }
        __syncthreads();
#pragma unroll
        for (int kt = 0; kt < 2; ++kt) {
            bf16x8 a = *(const bf16x8*)&Ash[wave * 16 + col][kt * 32 + kq * 8];
#pragma unroll
            for (int nt = 0; nt < 4; ++nt) {
                bf16x8 bb = *(const bf16x8*)&Bsh[nt * 16 + col][kt * 32 + kq * 8];
                acc[nt] = MFMA(a, bb, acc[nt], 0, 0, 0);
            }
        }
        __syncthreads();
    }
#pragma unroll
    for (int nt = 0; nt < 4; ++nt) {
        const int n = h0 + nt * 16 + col;
        const float bv = bih[n] + bhh[n];
#pragma unroll
        for (int reg = 0; reg < 4; ++reg) {
            const int m = bt0 + wave * 16 + kq * 4 + reg;
            out[(size_t)m * 512 + n] = acc[nt][reg] + bv;
        }
    }
}

// ---------------------------------------------------------------------------
// Kernel 2: recurrence with M=16 batch-rows per MFMA (vs round-1's M=1
// broadcast -> 16x effective matrix throughput per step-iteration).
// 8 blocks = 2 batch-groups(16) x 4 column-slices(128 cols). 256 threads,
// 4 waves x 32 cols; weights 128 VGPR/lane (launch_bounds(256,1): 1 wave/SIMD
// -> up to 512 VGPR, no spill). Lagrange history is register-resident in the
// output-owning lane; producers ship PRE-COMBINED bf16 h_read values, so the
// consumer deposit is a bit-move (numerics identical to the local path).
// lgkm-only barriers; poll loads issued right after barA so the agent-scope
// mailbox RT (IC-level) hides under the own-K MFMAs.
// ---------------------------------------------------------------------------
#define TT  1024
#define LDA 520   // 16-batch A-panel row stride (elems); 520*2B%128B != 0 -> 2-way max

__global__ __launch_bounds__(256, 1) void lagrange_rnn_kernel(
    const float* __restrict__ Whh, const float* __restrict__ kern,
    float* __restrict__ out, u64* __restrict__ mbox)
{
    const int id   = blockIdx.x;          // 0..7
    const int g    = id >> 2;             // batch group: batches [16g, 16g+16)
    const int p    = id & 3;              // column slice: cols [128p, 128p+128)
    const int tid  = threadIdx.x;
    const int w    = tid >> 6, lane = tid & 63;
    const int col  = lane & 15, kq = lane >> 4;

    __shared__ unsigned short Apan[2][16][LDA];   // parity-dbuf bf16 h_read panel

    for (int i = tid; i < 2 * 16 * LDA; i += 256)
        ((unsigned short*)Apan)[i] = 0;

    // --- weights K-reordered: wf[ct][j] <-> K-tile (4p+j)&15 (j=0..3 own slice)
    const int n0 = p * 128 + w * 32 + col;
    bf16x8 wf[2][16];
#pragma unroll
    for (int ct = 0; ct < 2; ++ct) {
        const float* wr = Whh + (size_t)(n0 + ct * 16) * 512 + kq * 8;
#pragma unroll
        for (int j = 0; j < 16; ++j) {
            const int ktg = ((j + 4 * p) & 15) * 32;
            const float4 lo = *(const float4*)(wr + ktg);
            const float4 hi = *(const float4*)(wr + ktg + 4);
            bf16x8 v;
            v[0]=(__bf16)lo.x; v[1]=(__bf16)lo.y; v[2]=(__bf16)lo.z; v[3]=(__bf16)lo.w;
            v[4]=(__bf16)hi.x; v[5]=(__bf16)hi.y; v[6]=(__bf16)hi.z; v[7]=(__bf16)hi.w;
            wf[ct][j] = v;
        }
    }

    const float k0 = kern[0], k1 = kern[1], k2 = kern[2], k3 = kern[3];

    // --- per-lane outputs: batch = 16g + kq*4 + r (MFMA C/D row), cols n0, n0+16
    const int b0 = g * 16;
    float* pb[4];
#pragma unroll
    for (int r = 0; r < 4; ++r)
        pb[r] = out + (size_t)(b0 + kq * 4 + r) * TT * 512 + n0;

    float xr[2][4], h1[2][4], h2[2][4], pp[2][4];
#pragma unroll
    for (int c = 0; c < 2; ++c)
#pragma unroll
        for (int r = 0; r < 4; ++r) { xr[c][r]=0.f; h1[c][r]=0.f; h2[c][r]=0.f; pp[c][r]=0.f; }

    const int q0 = (p + 1) & 3, q1 = (p + 2) & 3, q2 = (p + 3) & 3;
    const int arow = (lane & 15) * LDA + kq * 8;   // MFMA A-frag: row=lane&15, k-slice kq*8

    __syncthreads();
#pragma unroll
    for (int r = 0; r < 4; ++r) { xr[0][r] = pb[r][0]; xr[1][r] = pb[r][16]; }

    for (int t = 0; t < TT; ++t) {
        const int rb = t & 1, wb = rb ^ 1;

        lds_barrier();   // A[rb] own-col deposits (prev tail) visible; globals fly on

        // --- xp(t+1) prefetch (full-step slack; lgkm barriers don't drain vmcnt)
        float xn[2][4];
#pragma unroll
        for (int r = 0; r < 4; ++r) {
            xn[0][r] = pb[r][512];
            xn[1][r] = pb[r][512 + 16];
        }

        // --- issue poll loads EARLY (flight overlaps own-K MFMAs)
        u64 v[12];
        const u64* mp0 = mbox + ((size_t)(g * 4 + q0) * 2 + rb) * 1024 + (size_t)tid * 4;
        const u64* mp1 = mbox + ((size_t)(g * 4 + q1) * 2 + rb) * 1024 + (size_t)tid * 4;
        const u64* mp2 = mbox + ((size_t)(g * 4 + q2) * 2 + rb) * 1024 + (size_t)tid * 4;
        if (t) {
#pragma unroll
            for (int i = 0; i < 4; ++i) v[i]     = __hip_atomic_load(mp0 + i, __ATOMIC_RELAXED, AGENT);
#pragma unroll
            for (int i = 0; i < 4; ++i) v[4 + i] = __hip_atomic_load(mp1 + i, __ATOMIC_RELAXED, AGENT);
#pragma unroll
            for (int i = 0; i < 4; ++i) v[8 + i] = __hip_atomic_load(mp2 + i, __ATOMIC_RELAXED, AGENT);
        }

        // --- own-K MFMAs (j=0..3): operands deposited locally last step
        const unsigned short* Ar = &Apan[rb][0][0];
        f32x4 aA0 = (f32x4){0,0,0,0}, aA1 = (f32x4){0,0,0,0};
        f32x4 aB0 = (f32x4){0,0,0,0}, aB1 = (f32x4){0,0,0,0};
#pragma unroll
        for (int j = 0; j < 4; ++j) {
            bf16x8 a = *(const bf16x8*)(Ar + arow + ((j + 4 * p) & 15) * 32);
            aA0 = MFMA(a, wf[0][j], aA0, 0, 0, 0);
            aA1 = MFMA(a, wf[1][j], aA1, 0, 0, 0);
        }

        // --- complete poll (batched retry sweeps), deposit peer h_read (bit-move)
        if (t) {
            const unsigned want = (unsigned)t;
            bool again;
            do {
                again = false;
#pragma unroll
                for (int i = 0; i < 4; ++i)
                    if ((unsigned)(v[i] >> 32) != want)     { v[i]     = __hip_atomic_load(mp0 + i, __ATOMIC_RELAXED, AGENT); again = true; }
#pragma unroll
                for (int i = 0; i < 4; ++i)
                    if ((unsigned)(v[4+i] >> 32) != want)   { v[4+i]   = __hip_atomic_load(mp1 + i, __ATOMIC_RELAXED, AGENT); again = true; }
#pragma unroll
                for (int i = 0; i < 4; ++i)
                    if ((unsigned)(v[8+i] >> 32) != want)   { v[8+i]   = __hip_atomic_load(mp2 + i, __ATOMIC_RELAXED, AGENT); again = true; }
            } while (again);
#pragma unroll
            for (int i = 0; i < 4; ++i) {
                const unsigned pay = (unsigned)v[i];
                Apan[rb][kq * 4 + i][q0 * 128 + w * 32 + col]      = (unsigned short)pay;
                Apan[rb][kq * 4 + i][q0 * 128 + w * 32 + col + 16] = (unsigned short)(pay >> 16);
            }
#pragma unroll
            for (int i = 0; i < 4; ++i) {
                const unsigned pay = (unsigned)v[4 + i];
                Apan[rb][kq * 4 + i][q1 * 128 + w * 32 + col]      = (unsigned short)pay;
                Apan[rb][kq * 4 + i][q1 * 128 + w * 32 + col + 16] = (unsigned short)(pay >> 16);
            }
#pragma unroll
            for (int i = 0; i < 4; ++i) {
                const unsigned pay = (unsigned)v[8 + i];
                Apan[rb][kq * 4 + i][q2 * 128 + w * 32 + col]      = (unsigned short)pay;
                Apan[rb][kq * 4 + i][q2 * 128 + w * 32 + col + 16] = (unsigned short)(pay >> 16);
            }
        }

        lds_barrier();   // peer deposits visible

        // --- peer-K MFMAs (j=4..15), 4 chains for ILP
#pragma unroll
        for (int j = 4; j < 8; ++j) {
            bf16x8 a = *(const bf16x8*)(Ar + arow + ((j + 4 * p) & 15) * 32);
            aA0 = MFMA(a, wf[0][j], aA0, 0, 0, 0);
            aA1 = MFMA(a, wf[1][j], aA1, 0, 0, 0);
        }
#pragma unroll
        for (int j = 8; j < 16; ++j) {
            bf16x8 a = *(const bf16x8*)(Ar + arow + ((j + 4 * p) & 15) * 32);
            aB0 = MFMA(a, wf[0][j], aB0, 0, 0, 0);
            aB1 = MFMA(a, wf[1][j], aB1, 0, 0, 0);
        }

        // --- tail: tanh -> ship pre-combined h_read(t+1) (FIRST) -> states ->
        //     register ring update -> own A[wb] deposit
        u64* ms = mbox + ((size_t)(g * 4 + p) * 2 + wb) * 1024 + (size_t)tid * 4;
        const u64 tag = (u64)(unsigned)(t + 1) << 32;
#pragma unroll
        for (int r = 0; r < 4; ++r) {
            const float hv0 = fast_tanh(xr[0][r] + aA0[r] + aB0[r]);
            const float hv1 = fast_tanh(xr[1][r] + aA1[r] + aB1[r]);
            const float nh0 = k0 * hv0 + pp[0][r];
            const float nh1 = k0 * hv1 + pp[1][r];
            union { __bf16 h; unsigned short u; } u0, u1;
            u0.h = (__bf16)nh0; u1.h = (__bf16)nh1;
            __hip_atomic_store(&ms[r], tag | (u64)(u0.u | ((unsigned)u1.u << 16)),
                               __ATOMIC_RELAXED, AGENT);
            pp[0][r] = k1 * hv0 + k2 * h1[0][r] + k3 * h2[0][r];
            pp[1][r] = k1 * hv1 + k2 * h1[1][r] + k3 * h2[1][r];
            h2[0][r] = h1[0][r]; h1[0][r] = hv0;
            h2[1][r] = h1[1][r]; h1[1][r] = hv1;
            pb[r][0]  = hv0;                       // states (fire-and-forget)
            pb[r][16] = hv1;
            Apan[wb][kq * 4 + r][n0]      = u0.u;  // own-col deposit for t+1
            Apan[wb][kq * 4 + r][n0 + 16] = u1.u;
            xr[0][r] = xn[0][r]; xr[1][r] = xn[1][r];
            pb[r] += 512;
        }
    }

    // --- final state h(1023) from the register ring
    float* o2 = out + (size_t)32 * TT * 512;
#pragma unroll
    for (int r = 0; r < 4; ++r) {
        o2[(size_t)(b0 + kq * 4 + r) * 512 + n0]      = h1[0][r];
        o2[(size_t)(b0 + kq * 4 + r) * 512 + n0 + 16] = h1[1][r];
    }
}

// ---------------------------------------------------------------------------
extern "C" void kernel_launch(void* const* d_in, const int* in_sizes, int n_in,
                              void* d_out, int out_size, void* d_ws, size_t ws_size,
                              hipStream_t stream) {
    const float* x    = (const float*)d_in[0];   // [32,1024,512]
    const float* Wih  = (const float*)d_in[1];   // [512,512]
    const float* Whh  = (const float*)d_in[2];   // [512,512]
    const float* bih  = (const float*)d_in[3];   // [512]
    const float* bhh  = (const float*)d_in[4];   // [512]
    const float* kern = (const float*)d_in[5];   // [4]
    float* out = (float*)d_out;

    // mailbox: 8 panels (2 groups x 4 slices) x 2 parity x 1024 tagged u64 = 128 KB.
    // No init needed: exact tag match; workspace poison can't match a tag.
    u64* mbox = (u64*)d_ws;

    dim3 g1(512, 8, 1);
    xproj_gemm_kernel<<<g1, 256, 0, stream>>>(x, Wih, bih, bhh, out);
    lagrange_rnn_kernel<<<8, 256, 0, stream>>>(Whh, kern, out, mbox);
}